// Round 2
// baseline (75.708 us; speedup 1.0000x reference)
//
#include <hip/hip_runtime.h>

// NLM smoothing: x[B=8, H=256, W=256, C=8] fp32, K=5, sigma=1, h=1, reflect pad.
//
// v3: vertical register blocking. Each thread computes RPT=4 vertically
// adjacent output pixels, sharing LDS neighbor reads across centers:
// 8 rows x 5 cols = 40 staged pixels serve 4 outputs -> 80 ds_read_b128 +
// 40 ds_read_b32 per thread (vs 200+100 in v2), a 2.5x cut on the
// bottleneck LDS pipe. Lanes stay contiguous in j (16 B stride,
// conflict-free) -- horizontal blocking would reintroduce the 32 B-stride
// 4-way bank conflict removed in v2.
// Kept from v2: SoA float4 LDS planes; w ∝ exp(2*c·p - |p|^2 - 0.5*(dr^2+dc^2))
// with |p|^2 precomputed per staged pixel (exp(-|c|^2) cancels in norm).

#define BATCH 8
#define NX 256
#define NY 256
#define HALO 2
#define TSJ 32
#define TSI 32
#define RPT 4                 // output rows per thread
#define LW (TSJ + 2 * HALO)   // 36
#define LH (TSI + 2 * HALO)   // 36
#define NPIX (LW * LH)        // 1296

__device__ __forceinline__ int reflect_idx(int v) {
    // valid for v in [-2, 257] with N=256
    if (v < 0) v = -v;
    if (v > NY - 1) v = 2 * (NY - 1) - v;
    return v;
}

__global__ __launch_bounds__(256, 2) void nlm_kernel(const float4* __restrict__ xv,
                                                     float4* __restrict__ ov) {
    __shared__ float4 t0[NPIX];   // channels 0-3
    __shared__ float4 t1[NPIX];   // channels 4-7
    __shared__ float  tn[NPIX];   // |p|^2 per pixel

    const int t = threadIdx.x;
    const int bj0 = blockIdx.x * TSJ;
    const int bi0 = blockIdx.y * TSI;
    const int b = blockIdx.z;
    const int bbase = b * (NX * NY);

    // ---- stage 36x36 tile (with reflect halo) into LDS, SoA planes + norms ----
#pragma unroll
    for (int s0 = 0; s0 < NPIX; s0 += 256) {
        const int p = s0 + t;
        if (p < NPIX) {
            const int lr = p / LW;
            const int lc = p - lr * LW;
            const int gi = reflect_idx(bi0 + lr - HALO);
            const int gj = reflect_idx(bj0 + lc - HALO);
            const int gidx = (bbase + gi * NY + gj) * 2;
            const float4 v0 = xv[gidx + 0];
            const float4 v1 = xv[gidx + 1];
            t0[p] = v0;
            t1[p] = v1;
            tn[p] = v0.x * v0.x + v0.y * v0.y + v0.z * v0.z + v0.w * v0.w +
                    v1.x * v1.x + v1.y * v1.y + v1.z * v1.z + v1.w * v1.w;
        }
    }
    __syncthreads();

    // ---- per-thread: 4 vertically adjacent pixels ----
    const int tj = t & (TSJ - 1);        // 0..31, contiguous within wave half
    const int ti = (t >> 5) * RPT;       // 0,4,...,28

    float4 cs0[RPT], cs1[RPT];           // pre-doubled centers (2*c)
#pragma unroll
    for (int k = 0; k < RPT; ++k) {
        const int cpix = (ti + HALO + k) * LW + (tj + HALO);
        const float4 c0 = t0[cpix];
        const float4 c1 = t1[cpix];
        cs0[k] = make_float4(2.f * c0.x, 2.f * c0.y, 2.f * c0.z, 2.f * c0.w);
        cs1[k] = make_float4(2.f * c1.x, 2.f * c1.y, 2.f * c1.z, 2.f * c1.w);
    }

    float4 acc0[RPT], acc1[RPT];
    float wsum[RPT];
#pragma unroll
    for (int k = 0; k < RPT; ++k) {
        acc0[k] = make_float4(0.f, 0.f, 0.f, 0.f);
        acc1[k] = make_float4(0.f, 0.f, 0.f, 0.f);
        wsum[k] = 0.f;
    }

#pragma unroll
    for (int r = 0; r < RPT + 2 * HALO; ++r) {        // 8 neighbor rows
#pragma unroll
        for (int dc = -HALO; dc <= HALO; ++dc) {      // 5 neighbor cols
            const int pix = (ti + r) * LW + (tj + HALO + dc);
            const float4 p0 = t0[pix];
            const float4 p1 = t1[pix];
            const float pn = tn[pix];
#pragma unroll
            for (int k = 0; k < RPT; ++k) {           // feed valid centers
                const int dr = r - HALO - k;
                if (dr >= -HALO && dr <= HALO) {      // compile-time
                    float a = (-0.5f * (float)(dr * dr + dc * dc)) - pn;
                    a = fmaf(cs0[k].x, p0.x, a);
                    a = fmaf(cs0[k].y, p0.y, a);
                    a = fmaf(cs0[k].z, p0.z, a);
                    a = fmaf(cs0[k].w, p0.w, a);
                    a = fmaf(cs1[k].x, p1.x, a);
                    a = fmaf(cs1[k].y, p1.y, a);
                    a = fmaf(cs1[k].z, p1.z, a);
                    a = fmaf(cs1[k].w, p1.w, a);

                    const float w = __expf(a);

                    acc0[k].x = fmaf(w, p0.x, acc0[k].x);
                    acc0[k].y = fmaf(w, p0.y, acc0[k].y);
                    acc0[k].z = fmaf(w, p0.z, acc0[k].z);
                    acc0[k].w = fmaf(w, p0.w, acc0[k].w);
                    acc1[k].x = fmaf(w, p1.x, acc1[k].x);
                    acc1[k].y = fmaf(w, p1.y, acc1[k].y);
                    acc1[k].z = fmaf(w, p1.z, acc1[k].z);
                    acc1[k].w = fmaf(w, p1.w, acc1[k].w);
                    wsum[k] += w;
                }
            }
        }
    }

#pragma unroll
    for (int k = 0; k < RPT; ++k) {
        const float inv = 1.0f / wsum[k];
        float4 o0, o1;
        o0.x = acc0[k].x * inv; o0.y = acc0[k].y * inv;
        o0.z = acc0[k].z * inv; o0.w = acc0[k].w * inv;
        o1.x = acc1[k].x * inv; o1.y = acc1[k].y * inv;
        o1.z = acc1[k].z * inv; o1.w = acc1[k].w * inv;
        const int oidx = (bbase + (bi0 + ti + k) * NY + (bj0 + tj)) * 2;
        ov[oidx + 0] = o0;
        ov[oidx + 1] = o1;
    }
}

extern "C" void kernel_launch(void* const* d_in, const int* in_sizes, int n_in,
                              void* d_out, int out_size, void* d_ws, size_t ws_size,
                              hipStream_t stream) {
    const float4* x = (const float4*)d_in[0];
    float4* out = (float4*)d_out;
    dim3 grid(NY / TSJ, NX / TSI, BATCH);  // 8 x 8 x 8 = 512 blocks
    nlm_kernel<<<grid, 256, 0, stream>>>(x, out);
}